// Round 6
// baseline (258.688 us; speedup 1.0000x reference)
//
#include <hip/hip_runtime.h>
#include <hip/hip_fp16.h>
#include <math.h>

#define N_NODES 100000
#define N_EDGES 1600000
#define F_IN    128
#define F_HID   64
#define F_OUT   40

#define BIN_SHIFT 8
#define NBINS     392          // ceil(100000 / 256) + slack
#define BIN_CAP   5120         // mean ~4082 -> generous headroom
#define FILL_BLOCKS 512
#define GEMM1_BLOCKS ((N_NODES + 63) / 64)
#define GEMM2_BLOCKS ((N_NODES + 63) / 64)
#define AGG_BLOCKS  ((N_NODES + 15) / 16)   // 16 nodes per 256-thread block (4/wave)

typedef unsigned int  uint;
typedef unsigned short ushort;
typedef __attribute__((ext_vector_type(8))) _Float16 half8;  // 4 VGPRs (MFMA A/B frag)
typedef __attribute__((ext_vector_type(4))) float f32x4;     // MFMA acc

__device__ __forceinline__ uint pack2h(float a, float b) {   // two f32 -> packed f16x2
    __half2 h = __floats2half2_rn(a, b);
    return *(const uint*)&h;
}
__device__ __forceinline__ ushort f2h(float f) {
    return __half_as_ushort(__float2half_rn(f));
}
// 8-feature accumulate: fmaf(fpext(f16), f32, f32) pattern-matches v_fma_mix_f32.
__device__ __forceinline__ void fma8(float* acc, uint4 hv, float w) {
    const __half2* hp = (const __half2*)&hv;
    #pragma unroll
    for (int j = 0; j < 4; ++j) {
        acc[2 * j]     = fmaf(__low2float(hp[j]),  w, acc[2 * j]);
        acc[2 * j + 1] = fmaf(__high2float(hp[j]), w, acc[2 * j + 1]);
    }
}

// ---- prep: bin cursors + W1^T f16 [64][128] + W2^T f16 [48][64] (rows 40-47 = 0) --
__global__ void prep_kernel(const float* __restrict__ W, const float* __restrict__ W2,
                            uint* __restrict__ Wt, uint* __restrict__ Wt2,
                            int* __restrict__ bcursor) {
    int tid = threadIdx.x;                        // 512 threads
    if (tid < NBINS) bcursor[tid] = tid * BIN_CAP;
    for (int i = tid; i < 4096; i += 512) {       // uint index: c*64 + kpair
        int c  = i >> 6;
        int kp = i & 63;
        Wt[i] = pack2h(W[(2 * kp) * F_HID + c], W[(2 * kp + 1) * F_HID + c]);
    }
    for (int i = tid; i < 1536; i += 512) {       // uint index: c*32 + kpair
        int c  = i >> 5;
        int kp = i & 31;
        float lo = (c < F_OUT) ? W2[(2 * kp) * F_OUT + c]     : 0.f;
        float hi = (c < F_OUT) ? W2[(2 * kp + 1) * F_OUT + c] : 0.f;
        Wt2[i] = pack2h(lo, hi);
    }
}

// ---------------- fused: binned edge scatter (blocks 0..511) | GEMM1 (rest) -------
// binfill: scatter packed (src | ldst<<17) into padded bins.
// gemm1 (MFMA f16): h1[N,64](f16) = f16(x) @ f16(W1); independent of binfill.
#define XPITCH 68   // uints per row (64 + 4 pad)
__global__ __launch_bounds__(256) void fillgemm_kernel(
        const int* __restrict__ src, const int* __restrict__ dst,
        int* __restrict__ bcursor, int* __restrict__ bins, int E,
        const float* __restrict__ x, const uint* __restrict__ Wt,
        ushort* __restrict__ h, int n) {
    __shared__ __align__(16) uint smem[2 * 64 * XPITCH];   // 34.8 KB union
    int tid = threadIdx.x;

    if (blockIdx.x < FILL_BLOCKS) {
        // ---------------- binfill path ----------------
        int* lcount = (int*)smem;
        int* gbase  = ((int*)smem) + NBINS;
        for (int i = tid; i < NBINS; i += 256) lcount[i] = 0;
        __syncthreads();
        int chunk = (E + FILL_BLOCKS - 1) / FILL_BLOCKS;
        int beg = blockIdx.x * chunk, end = min(E, beg + chunk);
        for (int e = beg + tid; e < end; e += 256)
            atomicAdd(&lcount[dst[e] >> BIN_SHIFT], 1);
        __syncthreads();
        for (int i = tid; i < NBINS; i += 256) {
            gbase[i] = lcount[i] ? atomicAdd(&bcursor[i], lcount[i]) : 0;
            lcount[i] = 0;
        }
        __syncthreads();
        for (int e = beg + tid; e < end; e += 256) {
            int d = dst[e];
            int b = d >> BIN_SHIFT;
            int p = atomicAdd(&lcount[b], 1);
            bins[gbase[b] + p] = src[e] | ((d & 255) << 17);
        }
        return;
    }

    // ---------------- gemm1 path ----------------
    uint* Xu = smem;
    uint* Wu = smem + 64 * XPITCH;
    int node0 = (blockIdx.x - FILL_BLOCKS) * 64;

    {
        int c = tid >> 2, qq = tid & 3;
        const uint4* gsrc = (const uint4*)&Wt[c * 64 + qq * 16];
        uint4* ldst = (uint4*)&Wu[c * XPITCH + qq * 16];
        #pragma unroll
        for (int j = 0; j < 4; ++j) ldst[j] = gsrc[j];
    }
    {
        int row = tid >> 2, qq = tid & 3;
        int node = node0 + row;
        uint4* ldst = (uint4*)&Xu[row * XPITCH + qq * 16];
        if (node < n) {
            const float4* gsrc = (const float4*)&x[(size_t)node * F_IN + qq * 32];
            #pragma unroll
            for (int j = 0; j < 4; ++j) {
                float4 a = gsrc[2 * j], b = gsrc[2 * j + 1];
                uint4 o;
                o.x = pack2h(a.x, a.y); o.y = pack2h(a.z, a.w);
                o.z = pack2h(b.x, b.y); o.w = pack2h(b.z, b.w);
                ldst[j] = o;
            }
        } else {
            uint4 z = make_uint4(0, 0, 0, 0);
            #pragma unroll
            for (int j = 0; j < 4; ++j) ldst[j] = z;
        }
    }
    __syncthreads();

    int wv   = tid >> 6;
    int lane = tid & 63;
    int lrow = lane & 15;
    int quad = lane >> 4;

    half8 bfrag[4][4];
    #pragma unroll
    for (int t = 0; t < 4; ++t)
        #pragma unroll
        for (int s = 0; s < 4; ++s)
            bfrag[t][s] = *(const half8*)&Wu[(t * 16 + lrow) * XPITCH + s * 16 + quad * 4];

    f32x4 acc[4];
    #pragma unroll
    for (int t = 0; t < 4; ++t) acc[t] = (f32x4){0.f, 0.f, 0.f, 0.f};

    #pragma unroll
    for (int s = 0; s < 4; ++s) {
        half8 afrag = *(const half8*)&Xu[(wv * 16 + lrow) * XPITCH + s * 16 + quad * 4];
        #pragma unroll
        for (int t = 0; t < 4; ++t)
            acc[t] = __builtin_amdgcn_mfma_f32_16x16x32_f16(afrag, bfrag[t][s], acc[t], 0, 0, 0);
    }

    #pragma unroll
    for (int t = 0; t < 4; ++t) {
        #pragma unroll
        for (int i = 0; i < 4; ++i) {
            int node = node0 + wv * 16 + quad * 4 + i;
            if (node < n) h[(size_t)node * F_HID + t * 16 + lrow] = f2h(acc[t][i]);
        }
    }
}

// ---------------- per-bin counting sort; emits rowstart/rowcnt/dinv/csr -----------
__global__ void binsort_kernel(const int* __restrict__ bcursor, const int* __restrict__ bins,
                               int* __restrict__ csr, int* __restrict__ rowstart,
                               int* __restrict__ rowcnt, float* __restrict__ dinv) {
    __shared__ int hist[256];
    __shared__ int scan[256];
    __shared__ int cur[256];
    __shared__ int sorted[BIN_CAP];
    int b = blockIdx.x, t = threadIdx.x;          // 512 threads
    int base = b * BIN_CAP;
    int cnt = bcursor[b] - base;
    if (t < 256) hist[t] = 0;
    __syncthreads();
    for (int i = t; i < cnt; i += 512)
        atomicAdd(&hist[(unsigned)bins[base + i] >> 17], 1);
    __syncthreads();
    int v = 0;
    if (t < 256) { v = hist[t]; scan[t] = v; }
    __syncthreads();
    for (int off = 1; off < 256; off <<= 1) {
        int u = (t < 256 && t >= off) ? scan[t - off] : 0;
        __syncthreads();
        if (t < 256) scan[t] += u;
        __syncthreads();
    }
    if (t < 256) {
        int excl = scan[t] - v;
        cur[t] = excl;
        int node = (b << BIN_SHIFT) + t;
        if (node < N_NODES) {
            rowstart[node] = base + excl;
            rowcnt[node]   = v;
            dinv[node] = rsqrtf((float)v + 1.0f);   // +1 self-loop
        }
    }
    __syncthreads();
    for (int i = t; i < cnt; i += 512) {
        int p   = bins[base + i];
        int pos = atomicAdd(&cur[(unsigned)p >> 17], 1);
        sorted[pos] = p & 0x1FFFF;
    }
    __syncthreads();
    for (int i = t; i < cnt; i += 512)
        csr[base + i] = sorted[i];
}

// ---------------- layer-1 gather + combine + ReLU (16 lanes/node, 4 nodes/wave) ---
// Straight-line 16-edge batch: 16 shfl -> 8 dwordx4 loads in flight -> 64 fma_mix.
// Invalid edges are zero-wgt padded (load row 0, L1-hot broadcast, x0.0).
__global__ void agg1_kernel(const int* __restrict__ rowstart, const int* __restrict__ rowcnt,
                            const int* __restrict__ csr, const float* __restrict__ dinv,
                            const ushort* __restrict__ h, const float* __restrict__ b,
                            ushort* __restrict__ out, int n) {
    int lane = threadIdx.x & 63;
    int sub  = lane >> 4;                         // node within wave (0..3)
    int l16  = lane & 15;
    int slot = l16 >> 3;                          // 0..1
    int c    = l16 & 7;                           // chunk -> features c*8..c*8+7
    int node = blockIdx.x * 16 + (threadIdx.x >> 6) * 4 + sub;
    if (node >= n) return;
    int beg = rowstart[node], end = beg + rowcnt[node];
    int lbase = (lane & 48) + slot;               // shfl source base: sub*16 + slot
    float acc[8] = {0.f,0.f,0.f,0.f,0.f,0.f,0.f,0.f};
    for (int base = beg; base < end; base += 16) {
        int idx = base + l16;
        int   sid = 0; float wgt = 0.f;
        if (idx < end) { sid = csr[idx]; wgt = dinv[sid]; }
        int   sa[8]; float w[8];
        #pragma unroll
        for (int g = 0; g < 8; ++g) {
            sa[g] = __shfl(sid, lbase + 2 * g);
            w[g]  = __shfl(wgt, lbase + 2 * g);
        }
        uint4 hv[8];
        #pragma unroll
        for (int g = 0; g < 8; ++g)
            hv[g] = *(const uint4*)&h[(size_t)sa[g] * F_HID + (c << 3)];
        #pragma unroll
        for (int g = 0; g < 8; ++g) fma8(acc, hv[g], w[g]);
    }
    #pragma unroll
    for (int k = 0; k < 8; ++k) acc[k] += __shfl_xor(acc[k], 8);   // slot0+slot1
    if (slot == 0) {
        float di  = dinv[node];
        float di2 = di * di;
        uint4 hs = *(const uint4*)&h[(size_t)node * F_HID + (c << 3)];
        const __half2* hp = (const __half2*)&hs;
        float4 b0  = *(const float4*)&b[c << 3];
        float4 b1v = *(const float4*)&b[(c << 3) + 4];
        float bb[8] = { b0.x, b0.y, b0.z, b0.w, b1v.x, b1v.y, b1v.z, b1v.w };
        float v[8];
        #pragma unroll
        for (int k = 0; k < 4; ++k) {
            v[2*k]   = fmaxf(fmaf(acc[2*k],   di, __low2float(hp[k])  * di2) + bb[2*k],   0.f);
            v[2*k+1] = fmaxf(fmaf(acc[2*k+1], di, __high2float(hp[k]) * di2) + bb[2*k+1], 0.f);
        }
        uint4 pk;
        pk.x = pack2h(v[0], v[1]); pk.y = pack2h(v[2], v[3]);
        pk.z = pack2h(v[4], v[5]); pk.w = pack2h(v[6], v[7]);
        *(uint4*)&out[(size_t)node * F_HID + (c << 3)] = pk;
    }
}

// ---- GEMM2 (MFMA): h2[N,64-pitch](f16) = out1[N,64](f16) @ W2[64,40]; cols 40-63 = 0.
// Clones gemm1's verified 16x16x32_f16 fragment/C-write mapping; A and B loaded
// straight from global (16B aligned), no LDS. 64 nodes/block, 4 waves x 3 col-tiles.
__global__ __launch_bounds__(256) void gemm2_kernel(const ushort* __restrict__ a,
        const uint* __restrict__ Wt2, ushort* __restrict__ h, int n) {
    int tid  = threadIdx.x;
    int wv   = tid >> 6;
    int lane = tid & 63;
    int lrow = lane & 15;
    int quad = lane >> 4;
    int node0 = blockIdx.x * 64;
    const uint* au = (const uint*)a;              // packed f16 pairs, 32 uints/row

    half8 bfrag[3][2];
    #pragma unroll
    for (int t = 0; t < 3; ++t)
        #pragma unroll
        for (int s = 0; s < 2; ++s)
            bfrag[t][s] = *(const half8*)&Wt2[(t * 16 + lrow) * 32 + s * 16 + quad * 4];

    f32x4 acc[3];
    #pragma unroll
    for (int t = 0; t < 3; ++t) acc[t] = (f32x4){0.f, 0.f, 0.f, 0.f};

    int arow = node0 + wv * 16 + lrow;            // reads past n land in ws (safe, unused)
    #pragma unroll
    for (int s = 0; s < 2; ++s) {
        half8 afrag = *(const half8*)&au[(size_t)arow * 32 + s * 16 + quad * 4];
        #pragma unroll
        for (int t = 0; t < 3; ++t)
            acc[t] = __builtin_amdgcn_mfma_f32_16x16x32_f16(afrag, bfrag[t][s], acc[t], 0, 0, 0);
    }

    #pragma unroll
    for (int t = 0; t < 3; ++t) {
        #pragma unroll
        for (int i = 0; i < 4; ++i) {
            int node = node0 + wv * 16 + quad * 4 + i;
            if (node < n) h[(size_t)node * 64 + t * 16 + lrow] = f2h(acc[t][i]);
        }
    }
    #pragma unroll
    for (int i = 0; i < 4; ++i) {                 // zero cols 48..63
        int node = node0 + wv * 16 + quad * 4 + i;
        if (node < n) h[(size_t)node * 64 + 48 + lrow] = 0;
    }
}

// ---------------- layer-2 gather + combine + log_softmax (16 lanes/node) ----------
// Same straight-line 8-deep gather; chunks 5..7 read zero padding.
__global__ void agg2_kernel(const int* __restrict__ rowstart, const int* __restrict__ rowcnt,
                            const int* __restrict__ csr, const float* __restrict__ dinv,
                            const ushort* __restrict__ h, const float* __restrict__ b,
                            float* __restrict__ out, int n) {
    int lane = threadIdx.x & 63;
    int sub  = lane >> 4;
    int l16  = lane & 15;
    int slot = l16 >> 3;
    int c    = l16 & 7;                           // chunks 0..4 carry the 40 features
    int node = blockIdx.x * 16 + (threadIdx.x >> 6) * 4 + sub;
    if (node >= n) return;
    int beg = rowstart[node], end = beg + rowcnt[node];
    int lbase = (lane & 48) + slot;
    float acc[8] = {0.f,0.f,0.f,0.f,0.f,0.f,0.f,0.f};
    for (int base = beg; base < end; base += 16) {
        int idx = base + l16;
        int   sid = 0; float wgt = 0.f;
        if (idx < end) { sid = csr[idx]; wgt = dinv[sid]; }
        int   sa[8]; float w[8];
        #pragma unroll
        for (int g = 0; g < 8; ++g) {
            sa[g] = __shfl(sid, lbase + 2 * g);
            w[g]  = __shfl(wgt, lbase + 2 * g);
        }
        uint4 hv[8];
        #pragma unroll
        for (int g = 0; g < 8; ++g)
            hv[g] = *(const uint4*)&h[(size_t)sa[g] * 64 + (c << 3)];
        #pragma unroll
        for (int g = 0; g < 8; ++g) fma8(acc, hv[g], w[g]);
    }
    #pragma unroll
    for (int k = 0; k < 8; ++k) acc[k] += __shfl_xor(acc[k], 8);
    bool active = (slot == 0) && (c < 5);
    float val[8];
    float mx = -INFINITY;
    if (active) {
        float di  = dinv[node];
        float di2 = di * di;
        uint4 hs = *(const uint4*)&h[(size_t)node * 64 + (c << 3)];
        const __half2* hp = (const __half2*)&hs;
        float4 b0  = *(const float4*)&b[c << 3];
        float4 b1v = *(const float4*)&b[(c << 3) + 4];
        float bb[8] = { b0.x, b0.y, b0.z, b0.w, b1v.x, b1v.y, b1v.z, b1v.w };
        #pragma unroll
        for (int k = 0; k < 4; ++k) {
            val[2*k]   = fmaf(acc[2*k],   di, __low2float(hp[k])  * di2) + bb[2*k];
            val[2*k+1] = fmaf(acc[2*k+1], di, __high2float(hp[k]) * di2) + bb[2*k+1];
        }
        #pragma unroll
        for (int k = 0; k < 8; ++k) mx = fmaxf(mx, val[k]);
    }
    #pragma unroll
    for (int off = 1; off < 8; off <<= 1) mx = fmaxf(mx, __shfl_xor(mx, off));
    float p = 0.f;
    if (active) {
        #pragma unroll
        for (int k = 0; k < 8; ++k) p += __expf(val[k] - mx);
    }
    #pragma unroll
    for (int off = 1; off < 8; off <<= 1) p += __shfl_xor(p, off);
    float lse = mx + __logf(p);
    if (active) {
        float4 o0, o1;
        o0.x = val[0] - lse; o0.y = val[1] - lse; o0.z = val[2] - lse; o0.w = val[3] - lse;
        o1.x = val[4] - lse; o1.y = val[5] - lse; o1.z = val[6] - lse; o1.w = val[7] - lse;
        float* orow = &out[(size_t)node * F_OUT + (c << 3)];
        *(float4*)orow       = o0;
        *(float4*)(orow + 4) = o1;
    }
}

extern "C" void kernel_launch(void* const* d_in, const int* in_sizes, int n_in,
                              void* d_out, int out_size, void* d_ws, size_t ws_size,
                              hipStream_t stream) {
    const float* x  = (const float*)d_in[0];
    const int*   ei = (const int*)d_in[1];
    const float* W1 = (const float*)d_in[2];
    const float* b1 = (const float*)d_in[3];
    const float* W2 = (const float*)d_in[4];
    const float* b2 = (const float*)d_in[5];
    const int* src = ei;
    const int* dst = ei + N_EDGES;

    // workspace layout (all chunks 16B-aligned)
    char* p = (char*)d_ws;
    int*    bcursor  = (int*)p;     p += (size_t)(NBINS + 8) * 4;
    int*    bins     = (int*)p;     p += (size_t)NBINS * BIN_CAP * 4;
    int*    csr_src  = (int*)p;     p += (size_t)NBINS * BIN_CAP * 4;
    int*    rowstart = (int*)p;     p += (size_t)(N_NODES + 4) * 4;
    int*    rowcnt   = (int*)p;     p += (size_t)(N_NODES + 4) * 4;
    float*  dinv     = (float*)p;   p += (size_t)N_NODES * 4;
    uint*   Wtb      = (uint*)p;    p += (size_t)4096 * 4;       // W1^T f16 [64][128]
    uint*   Wt2b     = (uint*)p;    p += (size_t)1536 * 4;       // W2^T f16 [48][64]
    ushort* h1b      = (ushort*)p;  p += (size_t)N_NODES * F_HID * 2;
    ushort* out1b    = (ushort*)p;  p += (size_t)N_NODES * F_HID * 2;
    ushort* h2b      = (ushort*)p;  p += ((size_t)N_NODES * 64 + 64) * 2;  // pitch 64
    float*  out      = (float*)d_out;

    prep_kernel    <<<1, 512, 0, stream>>>(W1, W2, Wtb, Wt2b, bcursor);
    fillgemm_kernel<<<FILL_BLOCKS + GEMM1_BLOCKS, 256, 0, stream>>>(
        src, dst, bcursor, bins, N_EDGES, x, Wtb, h1b, N_NODES);
    binsort_kernel <<<NBINS, 512, 0, stream>>>(bcursor, bins, csr_src, rowstart, rowcnt, dinv);
    agg1_kernel    <<<AGG_BLOCKS, 256, 0, stream>>>(rowstart, rowcnt, csr_src, dinv,
                                                    h1b, b1, out1b, N_NODES);
    gemm2_kernel   <<<GEMM2_BLOCKS, 256, 0, stream>>>(out1b, Wt2b, h2b, N_NODES);
    agg2_kernel    <<<AGG_BLOCKS, 256, 0, stream>>>(rowstart, rowcnt, csr_src, dinv,
                                                    h2b, b2, out, N_NODES);
}

// Round 8
// 254.493 us; speedup vs baseline: 1.0165x; 1.0165x over previous
//
#include <hip/hip_runtime.h>
#include <hip/hip_fp16.h>
#include <math.h>

#define N_NODES 100000
#define N_EDGES 1600000
#define F_IN    128
#define F_HID   64
#define F_OUT   40

#define BIN_SHIFT 8
#define NBINS     392          // ceil(100000 / 256) + slack
#define BIN_CAP   5120         // mean ~4082 -> generous headroom
#define FILL_BLOCKS 512
#define GEMM1_BLOCKS ((N_NODES + 63) / 64)
#define GEMM2_BLOCKS ((N_NODES + 63) / 64)
#define AGG_BLOCKS  ((N_NODES + 15) / 16)   // 16 nodes per 256-thread block (4/wave)

typedef unsigned int  uint;
typedef unsigned short ushort;
typedef __attribute__((ext_vector_type(8))) _Float16 half8;  // 4 VGPRs (MFMA A/B frag)
typedef __attribute__((ext_vector_type(4))) float f32x4;     // MFMA acc

__device__ __forceinline__ uint pack2h(float a, float b) {   // two f32 -> packed f16x2
    __half2 h = __floats2half2_rn(a, b);
    return *(const uint*)&h;
}
__device__ __forceinline__ ushort f2h(float f) {
    return __half_as_ushort(__float2half_rn(f));
}
// 8-feature accumulate: fmaf(fpext(f16), f32, f32) pattern-matches v_fma_mix_f32.
__device__ __forceinline__ void fma8(float* acc, uint4 hv, float w) {
    const __half2* hp = (const __half2*)&hv;
    #pragma unroll
    for (int j = 0; j < 4; ++j) {
        acc[2 * j]     = fmaf(__low2float(hp[j]),  w, acc[2 * j]);
        acc[2 * j + 1] = fmaf(__high2float(hp[j]), w, acc[2 * j + 1]);
    }
}

// ---- prep: bin cursors + W1^T f16 [64][128] + W2^T f16 [48][64] (rows 40-47 = 0) --
__global__ void prep_kernel(const float* __restrict__ W, const float* __restrict__ W2,
                            uint* __restrict__ Wt, uint* __restrict__ Wt2,
                            int* __restrict__ bcursor) {
    int tid = threadIdx.x;                        // 512 threads
    if (tid < NBINS) bcursor[tid] = tid * BIN_CAP;
    for (int i = tid; i < 4096; i += 512) {       // uint index: c*64 + kpair
        int c  = i >> 6;
        int kp = i & 63;
        Wt[i] = pack2h(W[(2 * kp) * F_HID + c], W[(2 * kp + 1) * F_HID + c]);
    }
    for (int i = tid; i < 1536; i += 512) {       // uint index: c*32 + kpair
        int c  = i >> 5;
        int kp = i & 31;
        float lo = (c < F_OUT) ? W2[(2 * kp) * F_OUT + c]     : 0.f;
        float hi = (c < F_OUT) ? W2[(2 * kp + 1) * F_OUT + c] : 0.f;
        Wt2[i] = pack2h(lo, hi);
    }
}

// ---------------- fused: binned edge scatter (blocks 0..511) | GEMM1 (rest) -------
// binfill: scatter packed (src | ldst<<17) into padded bins.
// gemm1 (MFMA f16): h1[N,64](f16) = f16(x) @ f16(W1); independent of binfill.
#define XPITCH 68   // uints per row (64 + 4 pad)
__global__ __launch_bounds__(256) void fillgemm_kernel(
        const int* __restrict__ src, const int* __restrict__ dst,
        int* __restrict__ bcursor, int* __restrict__ bins, int E,
        const float* __restrict__ x, const uint* __restrict__ Wt,
        ushort* __restrict__ h, int n) {
    __shared__ __align__(16) uint smem[2 * 64 * XPITCH];   // 34.8 KB union
    int tid = threadIdx.x;

    if (blockIdx.x < FILL_BLOCKS) {
        // ---------------- binfill path ----------------
        int* lcount = (int*)smem;
        int* gbase  = ((int*)smem) + NBINS;
        for (int i = tid; i < NBINS; i += 256) lcount[i] = 0;
        __syncthreads();
        int chunk = (E + FILL_BLOCKS - 1) / FILL_BLOCKS;
        int beg = blockIdx.x * chunk, end = min(E, beg + chunk);
        for (int e = beg + tid; e < end; e += 256)
            atomicAdd(&lcount[dst[e] >> BIN_SHIFT], 1);
        __syncthreads();
        for (int i = tid; i < NBINS; i += 256) {
            gbase[i] = lcount[i] ? atomicAdd(&bcursor[i], lcount[i]) : 0;
            lcount[i] = 0;
        }
        __syncthreads();
        for (int e = beg + tid; e < end; e += 256) {
            int d = dst[e];
            int b = d >> BIN_SHIFT;
            int p = atomicAdd(&lcount[b], 1);
            bins[gbase[b] + p] = src[e] | ((d & 255) << 17);
        }
        return;
    }

    // ---------------- gemm1 path ----------------
    uint* Xu = smem;
    uint* Wu = smem + 64 * XPITCH;
    int node0 = (blockIdx.x - FILL_BLOCKS) * 64;

    {
        int c = tid >> 2, qq = tid & 3;
        const uint4* gsrc = (const uint4*)&Wt[c * 64 + qq * 16];
        uint4* ldst = (uint4*)&Wu[c * XPITCH + qq * 16];
        #pragma unroll
        for (int j = 0; j < 4; ++j) ldst[j] = gsrc[j];
    }
    {
        int row = tid >> 2, qq = tid & 3;
        int node = node0 + row;
        uint4* ldst = (uint4*)&Xu[row * XPITCH + qq * 16];
        if (node < n) {
            const float4* gsrc = (const float4*)&x[(size_t)node * F_IN + qq * 32];
            #pragma unroll
            for (int j = 0; j < 4; ++j) {
                float4 a = gsrc[2 * j], b = gsrc[2 * j + 1];
                uint4 o;
                o.x = pack2h(a.x, a.y); o.y = pack2h(a.z, a.w);
                o.z = pack2h(b.x, b.y); o.w = pack2h(b.z, b.w);
                ldst[j] = o;
            }
        } else {
            uint4 z = make_uint4(0, 0, 0, 0);
            #pragma unroll
            for (int j = 0; j < 4; ++j) ldst[j] = z;
        }
    }
    __syncthreads();

    int wv   = tid >> 6;
    int lane = tid & 63;
    int lrow = lane & 15;
    int quad = lane >> 4;

    half8 bfrag[4][4];
    #pragma unroll
    for (int t = 0; t < 4; ++t)
        #pragma unroll
        for (int s = 0; s < 4; ++s)
            bfrag[t][s] = *(const half8*)&Wu[(t * 16 + lrow) * XPITCH + s * 16 + quad * 4];

    f32x4 acc[4];
    #pragma unroll
    for (int t = 0; t < 4; ++t) acc[t] = (f32x4){0.f, 0.f, 0.f, 0.f};

    #pragma unroll
    for (int s = 0; s < 4; ++s) {
        half8 afrag = *(const half8*)&Xu[(wv * 16 + lrow) * XPITCH + s * 16 + quad * 4];
        #pragma unroll
        for (int t = 0; t < 4; ++t)
            acc[t] = __builtin_amdgcn_mfma_f32_16x16x32_f16(afrag, bfrag[t][s], acc[t], 0, 0, 0);
    }

    #pragma unroll
    for (int t = 0; t < 4; ++t) {
        #pragma unroll
        for (int i = 0; i < 4; ++i) {
            int node = node0 + wv * 16 + quad * 4 + i;
            if (node < n) h[(size_t)node * F_HID + t * 16 + lrow] = f2h(acc[t][i]);
        }
    }
}

// ---------------- per-bin counting sort; emits rowstart/rowcnt/dinv/csr -----------
__global__ void binsort_kernel(const int* __restrict__ bcursor, const int* __restrict__ bins,
                               int* __restrict__ csr, int* __restrict__ rowstart,
                               int* __restrict__ rowcnt, float* __restrict__ dinv) {
    __shared__ int hist[256];
    __shared__ int scan[256];
    __shared__ int cur[256];
    __shared__ int sorted[BIN_CAP];
    int b = blockIdx.x, t = threadIdx.x;          // 512 threads
    int base = b * BIN_CAP;
    int cnt = bcursor[b] - base;
    if (t < 256) hist[t] = 0;
    __syncthreads();
    for (int i = t; i < cnt; i += 512)
        atomicAdd(&hist[(unsigned)bins[base + i] >> 17], 1);
    __syncthreads();
    int v = 0;
    if (t < 256) { v = hist[t]; scan[t] = v; }
    __syncthreads();
    for (int off = 1; off < 256; off <<= 1) {
        int u = (t < 256 && t >= off) ? scan[t - off] : 0;
        __syncthreads();
        if (t < 256) scan[t] += u;
        __syncthreads();
    }
    if (t < 256) {
        int excl = scan[t] - v;
        cur[t] = excl;
        int node = (b << BIN_SHIFT) + t;
        if (node < N_NODES) {
            rowstart[node] = base + excl;
            rowcnt[node]   = v;
            dinv[node] = rsqrtf((float)v + 1.0f);   // +1 self-loop
        }
    }
    __syncthreads();
    for (int i = t; i < cnt; i += 512) {
        int p   = bins[base + i];
        int pos = atomicAdd(&cur[(unsigned)p >> 17], 1);
        sorted[pos] = p & 0x1FFFF;
    }
    __syncthreads();
    for (int i = t; i < cnt; i += 512)
        csr[base + i] = sorted[i];
}

// ---------------- layer-1 gather + combine + ReLU (16 lanes/node, 4 nodes/wave) ---
// Straight-line 16-edge batch: 16 shfl -> 8 dwordx4 loads in flight -> 64 fma_mix.
// Invalid edges are zero-wgt padded (load row 0, L1-hot broadcast, x0.0).
__global__ void agg1_kernel(const int* __restrict__ rowstart, const int* __restrict__ rowcnt,
                            const int* __restrict__ csr, const float* __restrict__ dinv,
                            const ushort* __restrict__ h, const float* __restrict__ b,
                            ushort* __restrict__ out, int n) {
    int lane = threadIdx.x & 63;
    int sub  = lane >> 4;                         // node within wave (0..3)
    int l16  = lane & 15;
    int slot = l16 >> 3;                          // 0..1
    int c    = l16 & 7;                           // chunk -> features c*8..c*8+7
    int node = blockIdx.x * 16 + (threadIdx.x >> 6) * 4 + sub;
    if (node >= n) return;
    int beg = rowstart[node], end = beg + rowcnt[node];
    int lbase = (lane & 48) + slot;               // shfl source base: sub*16 + slot
    float acc[8] = {0.f,0.f,0.f,0.f,0.f,0.f,0.f,0.f};
    for (int base = beg; base < end; base += 16) {
        int idx = base + l16;
        int   sid = 0; float wgt = 0.f;
        if (idx < end) { sid = csr[idx]; wgt = dinv[sid]; }
        int   sa[8]; float w[8];
        #pragma unroll
        for (int g = 0; g < 8; ++g) {
            sa[g] = __shfl(sid, lbase + 2 * g);
            w[g]  = __shfl(wgt, lbase + 2 * g);
        }
        uint4 hv[8];
        #pragma unroll
        for (int g = 0; g < 8; ++g)
            hv[g] = *(const uint4*)&h[(size_t)sa[g] * F_HID + (c << 3)];
        #pragma unroll
        for (int g = 0; g < 8; ++g) fma8(acc, hv[g], w[g]);
    }
    #pragma unroll
    for (int k = 0; k < 8; ++k) acc[k] += __shfl_xor(acc[k], 8);   // slot0+slot1
    if (slot == 0) {
        float di  = dinv[node];
        float di2 = di * di;
        uint4 hs = *(const uint4*)&h[(size_t)node * F_HID + (c << 3)];
        const __half2* hp = (const __half2*)&hs;
        float4 b0  = *(const float4*)&b[c << 3];
        float4 b1v = *(const float4*)&b[(c << 3) + 4];
        float bb[8] = { b0.x, b0.y, b0.z, b0.w, b1v.x, b1v.y, b1v.z, b1v.w };
        float v[8];
        #pragma unroll
        for (int k = 0; k < 4; ++k) {
            v[2*k]   = fmaxf(fmaf(acc[2*k],   di, __low2float(hp[k])  * di2) + bb[2*k],   0.f);
            v[2*k+1] = fmaxf(fmaf(acc[2*k+1], di, __high2float(hp[k]) * di2) + bb[2*k+1], 0.f);
        }
        uint4 pk;
        pk.x = pack2h(v[0], v[1]); pk.y = pack2h(v[2], v[3]);
        pk.z = pack2h(v[4], v[5]); pk.w = pack2h(v[6], v[7]);
        *(uint4*)&out[(size_t)node * F_HID + (c << 3)] = pk;
    }
}

// ---- GEMM2 (MFMA): split output. lo[N][32](f16, 64B line-aligned rows) = cols 0-31;
// hi[N][8](f16, 16B rows, 1.6MB -> L2-resident) = cols 32-39. No zero columns stored.
__global__ __launch_bounds__(256) void gemm2_kernel(const ushort* __restrict__ a,
        const uint* __restrict__ Wt2, ushort* __restrict__ lo, ushort* __restrict__ hi,
        int n) {
    int tid  = threadIdx.x;
    int wv   = tid >> 6;
    int lane = tid & 63;
    int lrow = lane & 15;
    int quad = lane >> 4;
    int node0 = blockIdx.x * 64;
    const uint* au = (const uint*)a;              // packed f16 pairs, 32 uints/row

    half8 bfrag[3][2];
    #pragma unroll
    for (int t = 0; t < 3; ++t)
        #pragma unroll
        for (int s = 0; s < 2; ++s)
            bfrag[t][s] = *(const half8*)&Wt2[(t * 16 + lrow) * 32 + s * 16 + quad * 4];

    f32x4 acc[3];
    #pragma unroll
    for (int t = 0; t < 3; ++t) acc[t] = (f32x4){0.f, 0.f, 0.f, 0.f};

    int arow = node0 + wv * 16 + lrow;            // reads past n land in ws (safe, unused)
    #pragma unroll
    for (int s = 0; s < 2; ++s) {
        half8 afrag = *(const half8*)&au[(size_t)arow * 32 + s * 16 + quad * 4];
        #pragma unroll
        for (int t = 0; t < 3; ++t)
            acc[t] = __builtin_amdgcn_mfma_f32_16x16x32_f16(afrag, bfrag[t][s], acc[t], 0, 0, 0);
    }

    #pragma unroll
    for (int t = 0; t < 2; ++t) {                 // cols 0..31 -> lo
        #pragma unroll
        for (int i = 0; i < 4; ++i) {
            int node = node0 + wv * 16 + quad * 4 + i;
            if (node < n) lo[(size_t)node * 32 + t * 16 + lrow] = f2h(acc[t][i]);
        }
    }
    if (lrow < 8) {                               // cols 32..39 -> hi
        #pragma unroll
        for (int i = 0; i < 4; ++i) {
            int node = node0 + wv * 16 + quad * 4 + i;
            if (node < n) hi[(size_t)node * 8 + lrow] = f2h(acc[2][i]);
        }
    }
}

// ---------------- layer-2 gather + combine + log_softmax (16 lanes/node) ----------
// Chunks 0-3 gather lo (one 64B line/row), chunk 4 gathers hi (L2-resident),
// chunks 5-7 idle on memory. Same straight-line 8-deep batch.
__global__ void agg2_kernel(const int* __restrict__ rowstart, const int* __restrict__ rowcnt,
                            const int* __restrict__ csr, const float* __restrict__ dinv,
                            const ushort* __restrict__ lo, const ushort* __restrict__ hi,
                            const float* __restrict__ b, float* __restrict__ out, int n) {
    int lane = threadIdx.x & 63;
    int sub  = lane >> 4;
    int l16  = lane & 15;
    int slot = l16 >> 3;
    int c    = l16 & 7;                           // chunks 0..4 carry the 40 features
    int node = blockIdx.x * 16 + (threadIdx.x >> 6) * 4 + sub;
    if (node >= n) return;
    int beg = rowstart[node], end = beg + rowcnt[node];
    int lbase = (lane & 48) + slot;
    float acc[8] = {0.f,0.f,0.f,0.f,0.f,0.f,0.f,0.f};
    for (int base = beg; base < end; base += 16) {
        int idx = base + l16;
        int   sid = 0; float wgt = 0.f;
        if (idx < end) { sid = csr[idx]; wgt = dinv[sid]; }
        int   sa[8]; float w[8];
        #pragma unroll
        for (int g = 0; g < 8; ++g) {
            sa[g] = __shfl(sid, lbase + 2 * g);
            w[g]  = __shfl(wgt, lbase + 2 * g);
        }
        if (c < 4) {
            uint4 hv[8];
            #pragma unroll
            for (int g = 0; g < 8; ++g)
                hv[g] = *(const uint4*)&lo[(size_t)sa[g] * 32 + (c << 3)];
            #pragma unroll
            for (int g = 0; g < 8; ++g) fma8(acc, hv[g], w[g]);
        } else if (c == 4) {
            uint4 hv[8];
            #pragma unroll
            for (int g = 0; g < 8; ++g)
                hv[g] = *(const uint4*)&hi[(size_t)sa[g] * 8];
            #pragma unroll
            for (int g = 0; g < 8; ++g) fma8(acc, hv[g], w[g]);
        }
    }
    #pragma unroll
    for (int k = 0; k < 8; ++k) acc[k] += __shfl_xor(acc[k], 8);
    bool active = (slot == 0) && (c < 5);
    float val[8];
    float mx = -INFINITY;
    if (active) {
        float di  = dinv[node];
        float di2 = di * di;
        uint4 hs = (c < 4) ? *(const uint4*)&lo[(size_t)node * 32 + (c << 3)]
                           : *(const uint4*)&hi[(size_t)node * 8];
        const __half2* hp = (const __half2*)&hs;
        float4 b0  = *(const float4*)&b[c << 3];
        float4 b1v = *(const float4*)&b[(c << 3) + 4];
        float bb[8] = { b0.x, b0.y, b0.z, b0.w, b1v.x, b1v.y, b1v.z, b1v.w };
        #pragma unroll
        for (int k = 0; k < 4; ++k) {
            val[2*k]   = fmaf(acc[2*k],   di, __low2float(hp[k])  * di2) + bb[2*k];
            val[2*k+1] = fmaf(acc[2*k+1], di, __high2float(hp[k]) * di2) + bb[2*k+1];
        }
        #pragma unroll
        for (int k = 0; k < 8; ++k) mx = fmaxf(mx, val[k]);
    }
    #pragma unroll
    for (int off = 1; off < 8; off <<= 1) mx = fmaxf(mx, __shfl_xor(mx, off));
    float p = 0.f;
    if (active) {
        #pragma unroll
        for (int k = 0; k < 8; ++k) p += __expf(val[k] - mx);
    }
    #pragma unroll
    for (int off = 1; off < 8; off <<= 1) p += __shfl_xor(p, off);
    float lse = mx + __logf(p);
    if (active) {
        float4 o0, o1;
        o0.x = val[0] - lse; o0.y = val[1] - lse; o0.z = val[2] - lse; o0.w = val[3] - lse;
        o1.x = val[4] - lse; o1.y = val[5] - lse; o1.z = val[6] - lse; o1.w = val[7] - lse;
        float* orow = &out[(size_t)node * F_OUT + (c << 3)];
        *(float4*)orow       = o0;
        *(float4*)(orow + 4) = o1;
    }
}

extern "C" void kernel_launch(void* const* d_in, const int* in_sizes, int n_in,
                              void* d_out, int out_size, void* d_ws, size_t ws_size,
                              hipStream_t stream) {
    const float* x  = (const float*)d_in[0];
    const int*   ei = (const int*)d_in[1];
    const float* W1 = (const float*)d_in[2];
    const float* b1 = (const float*)d_in[3];
    const float* W2 = (const float*)d_in[4];
    const float* b2 = (const float*)d_in[5];
    const int* src = ei;
    const int* dst = ei + N_EDGES;

    // workspace layout (all chunks 16B-aligned)
    char* p = (char*)d_ws;
    int*    bcursor  = (int*)p;     p += (size_t)(NBINS + 8) * 4;
    int*    bins     = (int*)p;     p += (size_t)NBINS * BIN_CAP * 4;
    int*    csr_src  = (int*)p;     p += (size_t)NBINS * BIN_CAP * 4;
    int*    rowstart = (int*)p;     p += (size_t)(N_NODES + 4) * 4;
    int*    rowcnt   = (int*)p;     p += (size_t)(N_NODES + 4) * 4;
    float*  dinv     = (float*)p;   p += (size_t)N_NODES * 4;
    uint*   Wtb      = (uint*)p;    p += (size_t)4096 * 4;       // W1^T f16 [64][128]
    uint*   Wt2b     = (uint*)p;    p += (size_t)1536 * 4;       // W2^T f16 [48][64]
    ushort* h1b      = (ushort*)p;  p += (size_t)N_NODES * F_HID * 2;
    ushort* out1b    = (ushort*)p;  p += (size_t)N_NODES * F_HID * 2;
    ushort* h2lo     = (ushort*)p;  p += (size_t)N_NODES * 32 * 2;        // cols 0-31
    ushort* h2hi     = (ushort*)p;  p += ((size_t)N_NODES * 8 + 64) * 2;  // cols 32-39
    float*  out      = (float*)d_out;

    prep_kernel    <<<1, 512, 0, stream>>>(W1, W2, Wtb, Wt2b, bcursor);
    fillgemm_kernel<<<FILL_BLOCKS + GEMM1_BLOCKS, 256, 0, stream>>>(
        src, dst, bcursor, bins, N_EDGES, x, Wtb, h1b, N_NODES);
    binsort_kernel <<<NBINS, 512, 0, stream>>>(bcursor, bins, csr_src, rowstart, rowcnt, dinv);
    agg1_kernel    <<<AGG_BLOCKS, 256, 0, stream>>>(rowstart, rowcnt, csr_src, dinv,
                                                    h1b, b1, out1b, N_NODES);
    gemm2_kernel   <<<GEMM2_BLOCKS, 256, 0, stream>>>(out1b, Wt2b, h2lo, h2hi, N_NODES);
    agg2_kernel    <<<AGG_BLOCKS, 256, 0, stream>>>(rowstart, rowcnt, csr_src, dinv,
                                                    h2lo, h2hi, b2, out, N_NODES);
}